// Round 1
// baseline (128.551 us; speedup 1.0000x reference)
//
#include <hip/hip_runtime.h>
#include <math.h>

constexpr int N_ELEM = 8192;
constexpr int BLK    = 256;
constexpr int NBLK   = N_ELEM / BLK;   // 32 row tiles
constexpr int JCH    = 32;             // j-chunks
constexpr int JLEN   = N_ELEM / JCH;   // 256 per chunk
constexpr float LAMBDA = 0.1f;

// ws layout (bytes):
//   [0,64)            : double dacc[8]  {0:bce_sum, 1:nf, 2:atot_raw, 3:btot_raw, 4:AB, 5:AA, 6:BB}
//   [64, 64+4N)       : float wm[N]
//   [64+4N, 64+8N)    : float rowA[N]   (raw: sum_j |v1_i - v1_j| * wm_j)
//   [64+8N, 64+12N)   : float rowB[N]
// total = 64 + 12*8192 = 98368 bytes

__device__ __forceinline__ float blockReduce(float v, float* sbuf) {
    int tx = threadIdx.x;
    sbuf[tx] = v;
    __syncthreads();
#pragma unroll
    for (int s = BLK / 2; s > 0; s >>= 1) {
        if (tx < s) sbuf[tx] += sbuf[tx + s];
        __syncthreads();
    }
    float r = sbuf[0];
    __syncthreads();
    return r;
}

// K1: bce partial sum, nf, wm
__global__ void k1_init(const float* __restrict__ inf, const int* __restrict__ lab,
                        const float* __restrict__ wt, double* dacc, float* wm) {
    __shared__ float sbuf[BLK];
    int i = blockIdx.x * BLK + threadIdx.x;
    float p = inf[i];
    int   y = lab[i];
    float w = wt[i];
    float logp   = fmaxf(logf(p), -100.0f);
    float log1mp = fmaxf(log1pf(-p), -100.0f);
    float yf = (float)y;
    float bce = w * -(yf * logp + (1.0f - yf) * log1mp);
    float m = (y == 0) ? 1.0f : 0.0f;
    wm[i] = w * m;

    float bsum = blockReduce(bce, sbuf);
    float msum = blockReduce(m, sbuf);
    if (threadIdx.x == 0) {
        atomicAdd(&dacc[0], (double)bsum);
        atomicAdd(&dacc[1], (double)msum);
    }
}

// K2: raw row sums.  grid (NBLK, JCH)
__global__ void k2_rowsums(const float* __restrict__ inf, const float* __restrict__ tgt,
                           const float* __restrict__ wm,
                           float* __restrict__ rowA, float* __restrict__ rowB) {
    __shared__ float s1[JLEN], s2[JLEN], sw[JLEN];
    int tx = threadIdx.x;
    int j0 = blockIdx.y * JLEN;
    s1[tx] = inf[j0 + tx];
    s2[tx] = tgt[j0 + tx];
    sw[tx] = wm[j0 + tx];
    __syncthreads();

    int i = blockIdx.x * BLK + tx;
    float v1 = inf[i], v2 = tgt[i];
    float sa = 0.f, sb = 0.f;
#pragma unroll 8
    for (int j = 0; j < JLEN; ++j) {
        float w = sw[j];
        sa += fabsf(v1 - s1[j]) * w;
        sb += fabsf(v2 - s2[j]) * w;
    }
    atomicAdd(&rowA[i], sa);
    atomicAdd(&rowB[i], sb);
}

// K3: atot_raw = sum_i rowA[i]*wm[i], btot_raw likewise
__global__ void k3_tot(const float* __restrict__ rowA, const float* __restrict__ rowB,
                       const float* __restrict__ wm, double* dacc) {
    __shared__ float sbuf[BLK];
    int i = blockIdx.x * BLK + threadIdx.x;
    float w = wm[i];
    float ta = rowA[i] * w;
    float tb = rowB[i] * w;
    float sa = blockReduce(ta, sbuf);
    float sb = blockReduce(tb, sbuf);
    if (threadIdx.x == 0) {
        atomicAdd(&dacc[2], (double)sa);
        atomicAdd(&dacc[3], (double)sb);
    }
}

// K4: double-centered products.  grid (NBLK, JCH)
__global__ void k4_center(const float* __restrict__ inf, const float* __restrict__ tgt,
                          const float* __restrict__ wm,
                          const float* __restrict__ rowA, const float* __restrict__ rowB,
                          double* dacc) {
    __shared__ float s1[JLEN], s2[JLEN], sw[JLEN], sra[JLEN], srb[JLEN];
    __shared__ float sbuf[BLK];
    int tx = threadIdx.x;

    double nf_d = dacc[1];
    float nf = (float)nf_d;
    float at = (float)(dacc[2] / (nf_d * nf_d));
    float bt = (float)(dacc[3] / (nf_d * nf_d));

    int j0 = blockIdx.y * JLEN;
    s1[tx]  = inf[j0 + tx];
    s2[tx]  = tgt[j0 + tx];
    sw[tx]  = wm[j0 + tx];
    sra[tx] = rowA[j0 + tx] / nf;
    srb[tx] = rowB[j0 + tx] / nf;
    __syncthreads();

    int i = blockIdx.x * BLK + tx;
    float v1 = inf[i], v2 = tgt[i];
    float wmi = wm[i];
    float pi = at - rowA[i] / nf;   // (a_tot - a_row[i])
    float qi = bt - rowB[i] / nf;

    float sab = 0.f, saa = 0.f, sbb = 0.f;
#pragma unroll 8
    for (int j = 0; j < JLEN; ++j) {
        float A = fabsf(v1 - s1[j]) - sra[j] + pi;
        float B = fabsf(v2 - s2[j]) - srb[j] + qi;
        float w = sw[j];
        float wA = w * A;
        sab += wA * B;
        saa += wA * A;
        sbb += w * B * B;
    }
    sab *= wmi; saa *= wmi; sbb *= wmi;

    float rab = blockReduce(sab, sbuf);
    float raa = blockReduce(saa, sbuf);
    float rbb = blockReduce(sbb, sbuf);
    if (tx == 0) {
        atomicAdd(&dacc[4], (double)rab);
        atomicAdd(&dacc[5], (double)raa);
        atomicAdd(&dacc[6], (double)rbb);
    }
}

// K5: finalize
__global__ void k5_final(const double* dacc, float* out) {
    double nf = dacc[1];
    double bce = dacc[0] / (double)N_ELEM;
    double inv = 1.0 / (nf * nf);
    double AB = dacc[4] * inv;
    double AA = dacc[5] * inv;
    double BB = dacc[6] * inv;
    double dcorr = (AB * AB) / (AA * BB);
    double ld = (double)LAMBDA * dcorr;
    out[0] = (float)(bce + ld);
    out[1] = (float)bce;
    out[2] = (float)ld;
}

extern "C" void kernel_launch(void* const* d_in, const int* in_sizes, int n_in,
                              void* d_out, int out_size, void* d_ws, size_t ws_size,
                              hipStream_t stream) {
    const float* inf = (const float*)d_in[0];
    const int*   lab = (const int*)d_in[1];
    const float* tgt = (const float*)d_in[2];
    const float* wt  = (const float*)d_in[3];
    float* out = (float*)d_out;

    double* dacc = (double*)d_ws;
    float*  wm   = (float*)((char*)d_ws + 64);
    float*  rowA = wm + N_ELEM;
    float*  rowB = rowA + N_ELEM;

    // zero accumulators + row sums (wm is fully overwritten by k1)
    hipMemsetAsync(d_ws, 0, 64 + (size_t)12 * N_ELEM, stream);

    k1_init<<<NBLK, BLK, 0, stream>>>(inf, lab, wt, dacc, wm);
    k2_rowsums<<<dim3(NBLK, JCH), BLK, 0, stream>>>(inf, tgt, wm, rowA, rowB);
    k3_tot<<<NBLK, BLK, 0, stream>>>(rowA, rowB, wm, dacc);
    k4_center<<<dim3(NBLK, JCH), BLK, 0, stream>>>(inf, tgt, wm, rowA, rowB, dacc);
    k5_final<<<1, 1, 0, stream>>>(dacc, out);
}

// Round 2
// 84.781 us; speedup vs baseline: 1.5163x; 1.5163x over previous
//
#include <hip/hip_runtime.h>
#include <math.h>

constexpr int N_ELEM = 8192;
constexpr int BLK    = 256;
constexpr int NBLK   = N_ELEM / BLK;   // 32
constexpr float LAMBDA = 0.1f;

// K2 tiling
constexpr int K2_BLK = 256;
constexpr int K2_IPT = 2;
constexpr int K2_IPB = K2_BLK * K2_IPT;        // 512 i per block
constexpr int K2_GX  = N_ELEM / K2_IPB;        // 16
constexpr int K2_JL  = 64;                     // j per chunk
constexpr int K2_GY  = N_ELEM / K2_JL;         // 128

// ws layout (bytes):
//   [0,128)        double dacc[16] {0:bce_sum,1:W,2:S1a,3:S2a,4:S1b,5:S2b,
//                                   6:P,7:Ra1,8:Ra2,9:Rb1,10:Rb2,11:Rab}
//   [128,132)      int cnt
//   [256, 256+128K)    float4 c[8192]   (v1, v2, wm, 0) compacted, zero-padded
//   [+64K)             float rowA[8192]
//   [+64K)             float rowB[8192]
// total = 256 + 131072 + 65536 = 196864 bytes (memset to 0 each call)

__device__ __forceinline__ float blockReduce(float v, float* sbuf) {
    int tx = threadIdx.x;
    sbuf[tx] = v;
    __syncthreads();
#pragma unroll
    for (int s = BLK / 2; s > 0; s >>= 1) {
        if (tx < s) sbuf[tx] += sbuf[tx + s];
        __syncthreads();
    }
    float r = sbuf[0];
    __syncthreads();
    return r;
}

// K1: BCE sum, masked moments, wave-ballot compaction of label==0 subset
__global__ void k1_init(const float* __restrict__ inf, const int* __restrict__ lab,
                        const float* __restrict__ tgt, const float* __restrict__ wt,
                        double* __restrict__ dacc, int* __restrict__ cnt,
                        float4* __restrict__ c) {
    __shared__ float sbuf[BLK];
    int i = blockIdx.x * BLK + threadIdx.x;
    float p = inf[i];
    int   y = lab[i];
    float w = wt[i];
    float t = tgt[i];

    float logp   = fmaxf(logf(p),    -100.0f);
    float log1mp = fmaxf(log1pf(-p), -100.0f);
    float yf = (float)y;
    float bce = w * -(yf * logp + (1.0f - yf) * log1mp);

    bool m = (y == 0);
    float wm = m ? w : 0.0f;

    // wave-aggregated compaction (order irrelevant: all downstream sums symmetric)
    unsigned long long bal = __ballot(m);
    int lane = threadIdx.x & 63;
    int pre  = __popcll(bal & ((1ull << lane) - 1ull));
    int wcnt = __popcll(bal);
    int base = 0;
    if (lane == 0) base = atomicAdd(cnt, wcnt);
    base = __shfl(base, 0);
    if (m) c[base + pre] = make_float4(p, t, w, 0.0f);

    float s;
    s = blockReduce(bce, sbuf);      if (!threadIdx.x) atomicAdd(&dacc[0], (double)s);
    s = blockReduce(wm, sbuf);       if (!threadIdx.x) atomicAdd(&dacc[1], (double)s);
    s = blockReduce(wm * p, sbuf);   if (!threadIdx.x) atomicAdd(&dacc[2], (double)s);
    s = blockReduce(wm * p * p, sbuf); if (!threadIdx.x) atomicAdd(&dacc[3], (double)s);
    s = blockReduce(wm * t, sbuf);   if (!threadIdx.x) atomicAdd(&dacc[4], (double)s);
    s = blockReduce(wm * t * t, sbuf); if (!threadIdx.x) atomicAdd(&dacc[5], (double)s);
}

// K2: single O(nc^2) pass over compacted subset.
// Per pair: P += wj*|d1|*|d2|, ra_i += wj*|d1|, rb_i += wj*|d2|
__global__ void __launch_bounds__(K2_BLK) k2_pairs(
        const float4* __restrict__ c, const int* __restrict__ cnt,
        float* __restrict__ rowA, float* __restrict__ rowB,
        double* __restrict__ dacc) {
    __shared__ float4 sc[K2_JL];
    __shared__ float sbuf[K2_BLK];

    int ncp = (*cnt + (K2_IPB - 1)) & ~(K2_IPB - 1);   // pad to 512
    int iBase = blockIdx.x * K2_IPB;
    int jBase = blockIdx.y * K2_JL;
    if (iBase >= ncp || jBase >= ncp) return;          // uniform exit

    int tx = threadIdx.x;
    if (tx < K2_JL) sc[tx] = c[jBase + tx];
    int i0 = iBase + tx, i1 = i0 + K2_BLK;
    float4 ci0 = c[i0], ci1 = c[i1];
    __syncthreads();

    float p0 = 0.f, ra0 = 0.f, rb0 = 0.f;
    float p1 = 0.f, ra1 = 0.f, rb1 = 0.f;
#pragma unroll 16
    for (int j = 0; j < K2_JL; ++j) {
        float4 cj = sc[j];
        float d1 = ci0.x - cj.x;
        float d2 = ci0.y - cj.y;
        p0  = fmaf(cj.z, fabsf(d1) * fabsf(d2), p0);
        ra0 = fmaf(cj.z, fabsf(d1), ra0);
        rb0 = fmaf(cj.z, fabsf(d2), rb0);
        float e1 = ci1.x - cj.x;
        float e2 = ci1.y - cj.y;
        p1  = fmaf(cj.z, fabsf(e1) * fabsf(e2), p1);
        ra1 = fmaf(cj.z, fabsf(e1), ra1);
        rb1 = fmaf(cj.z, fabsf(e2), rb1);
    }
    atomicAdd(&rowA[i0], ra0);
    atomicAdd(&rowB[i0], rb0);
    atomicAdd(&rowA[i1], ra1);
    atomicAdd(&rowB[i1], rb1);

    float pb = ci0.z * p0 + ci1.z * p1;   // wi factor for P
    pb = blockReduce(pb, sbuf);
    if (!tx) atomicAdd(&dacc[6], (double)pb);
}

// K3: row-sum moments Ra1,Ra2,Rb1,Rb2,Rab (padded rows have w=0)
__global__ void k3_rowmom(const float4* __restrict__ c,
                          const float* __restrict__ rowA, const float* __restrict__ rowB,
                          double* __restrict__ dacc) {
    __shared__ float sbuf[BLK];
    int i = blockIdx.x * BLK + threadIdx.x;
    float w  = c[i].z;
    float ra = rowA[i];
    float rb = rowB[i];
    float s;
    s = blockReduce(w * ra, sbuf);      if (!threadIdx.x) atomicAdd(&dacc[7],  (double)s);
    s = blockReduce(w * ra * ra, sbuf); if (!threadIdx.x) atomicAdd(&dacc[8],  (double)s);
    s = blockReduce(w * rb, sbuf);      if (!threadIdx.x) atomicAdd(&dacc[9],  (double)s);
    s = blockReduce(w * rb * rb, sbuf); if (!threadIdx.x) atomicAdd(&dacc[10], (double)s);
    s = blockReduce(w * ra * rb, sbuf); if (!threadIdx.x) atomicAdd(&dacc[11], (double)s);
}

// K4: assemble AA/BB/AB from moments (double), write outputs
__global__ void k4_final(const double* __restrict__ dacc, const int* __restrict__ cnt,
                         float* __restrict__ out) {
    double bce = dacc[0] / (double)N_ELEM;
    double nf  = (double)(*cnt);
    double W   = dacc[1];
    double S1a = dacc[2], S2a = dacc[3];
    double S1b = dacc[4], S2b = dacc[5];
    double P   = dacc[6];
    double Ra1 = dacc[7], Ra2 = dacc[8];
    double Rb1 = dacc[9], Rb2 = dacc[10], Rab = dacc[11];

    double n2 = nf * nf, n3 = n2 * nf, n4 = n2 * n2;

    double AAa = 2.0 * (W * S2a - S1a * S1a)
               - 4.0 * Ra2 / nf + 2.0 * W * Ra2 / n2
               + 4.0 * Ra1 * Ra1 / n2 - 4.0 * W * Ra1 * Ra1 / n3
               + W * W * Ra1 * Ra1 / n4;
    double BBa = 2.0 * (W * S2b - S1b * S1b)
               - 4.0 * Rb2 / nf + 2.0 * W * Rb2 / n2
               + 4.0 * Rb1 * Rb1 / n2 - 4.0 * W * Rb1 * Rb1 / n3
               + W * W * Rb1 * Rb1 / n4;
    double ABa = P
               - 4.0 * Rab / nf + 2.0 * W * Rab / n2
               + 4.0 * Ra1 * Rb1 / n2 - 4.0 * W * Ra1 * Rb1 / n3
               + W * W * Ra1 * Rb1 / n4;

    double AB = ABa / n2, AA = AAa / n2, BB = BBa / n2;
    double dcorr = (AB * AB) / (AA * BB);
    double ld = (double)LAMBDA * dcorr;
    out[0] = (float)(bce + ld);
    out[1] = (float)bce;
    out[2] = (float)ld;
}

extern "C" void kernel_launch(void* const* d_in, const int* in_sizes, int n_in,
                              void* d_out, int out_size, void* d_ws, size_t ws_size,
                              hipStream_t stream) {
    const float* inf = (const float*)d_in[0];
    const int*   lab = (const int*)d_in[1];
    const float* tgt = (const float*)d_in[2];
    const float* wt  = (const float*)d_in[3];
    float* out = (float*)d_out;

    double* dacc = (double*)d_ws;
    int*    cnt  = (int*)((char*)d_ws + 128);
    float4* c    = (float4*)((char*)d_ws + 256);
    float*  rowA = (float*)((char*)d_ws + 256 + 16 * N_ELEM);
    float*  rowB = rowA + N_ELEM;

    size_t total = 256 + (size_t)16 * N_ELEM + (size_t)8 * N_ELEM;
    hipMemsetAsync(d_ws, 0, total, stream);

    k1_init<<<NBLK, BLK, 0, stream>>>(inf, lab, tgt, wt, dacc, cnt, c);
    k2_pairs<<<dim3(K2_GX, K2_GY), K2_BLK, 0, stream>>>(c, cnt, rowA, rowB, dacc);
    k3_rowmom<<<NBLK, BLK, 0, stream>>>(c, rowA, rowB, dacc);
    k4_final<<<1, 1, 0, stream>>>(dacc, cnt, out);
}